// Round 12
// baseline (376.510 us; speedup 1.0000x reference)
//
#include <hip/hip_runtime.h>

#define N_NODES 50000
#define N_EDGES 800000
#define F_IN 128
#define F_HID 256
#define F_OUT 64

// ---------------- workspace layout (bytes) ----------------
// row_ptr @ 0.00 MiB: int[N+1]
// cnt     @ 0.25 MiB: int[N]
// cursor  @ 0.50 MiB: int[N]
// dinv    @ 0.75 MiB: f32[N]
// eidx    @ 1.00 MiB: int[E]          (3.2 MB)
// xb      @ 4.25 MiB: bf16[N,128]     (12.8 MB)  (pre-scaled by dinv)
// t2b     @ 17.5 MiB: bf16[N,64]      (6.4 MB)   (pre-scaled by dinv)

#define OFF_ROWPTR 0ull
#define OFF_CNT    (256ull << 10)
#define OFF_CURSOR (512ull << 10)
#define OFF_DINV   (768ull << 10)
#define OFF_EIDX   (1ull << 20)
#define OFF_XB     ((4ull << 20) + (256ull << 10))
#define OFF_T2B    ((17ull << 20) + (512ull << 10))

// ---------------- bf16 helpers ----------------

__device__ __forceinline__ unsigned f2bf(float f) {  // RNE to bf16 (low 16 bits)
    unsigned u = __float_as_uint(f);
    return (u + 0x7FFFu + ((u >> 16) & 1u)) >> 16;
}
__device__ __forceinline__ float bflo(unsigned u) { return __uint_as_float(u << 16); }
__device__ __forceinline__ float bfhi(unsigned u) { return __uint_as_float(u & 0xFFFF0000u); }

// ---------------- CSR build ----------------

__global__ void zero_cnt_kernel(int* __restrict__ cnt, int n) {
    int i = blockIdx.x * blockDim.x + threadIdx.x;
    if (i < n) cnt[i] = 0;
}

__global__ void hist_kernel(const int* __restrict__ cols, int* __restrict__ cnt, int e) {
    int i = blockIdx.x * blockDim.x + threadIdx.x;
    if (i < e) atomicAdd(&cnt[cols[i]], 1);
}

// single-block exclusive scan of cnt -> row_ptr (+ cursor copy + dinv)
__global__ __launch_bounds__(1024) void scan_kernel(const int* __restrict__ cnt,
                                                    int* __restrict__ row_ptr,
                                                    int* __restrict__ cursor,
                                                    float* __restrict__ dinv) {
    __shared__ int s[1024];
    const int CH = 49;
    int t = threadIdx.x;
    int base = t * CH;
    int ls = 0;
    for (int i = 0; i < CH; ++i) {
        int idx = base + i;
        if (idx < N_NODES) {
            int v = cnt[idx];
            ls += v;
            dinv[idx] = rsqrtf((float)v + 1.0f);  // +1 self loop
        }
    }
    s[t] = ls;
    __syncthreads();
    for (int off = 1; off < 1024; off <<= 1) {
        int v = (t >= off) ? s[t - off] : 0;
        __syncthreads();
        s[t] += v;
        __syncthreads();
    }
    int run = s[t] - ls;
    for (int i = 0; i < CH; ++i) {
        int idx = base + i;
        if (idx < N_NODES) {
            row_ptr[idx] = run;
            cursor[idx] = run;
            run += cnt[idx];
        }
    }
    if (t == 0) row_ptr[N_NODES] = N_EDGES;
}

// scatter edge ids into CSR slots AND convert x -> pre-scaled bf16 (same 800k grid)
__global__ void scatter_cvt_kernel(const int* __restrict__ rows, const int* __restrict__ cols,
                                   int* __restrict__ cursor, int* __restrict__ eidx,
                                   const float* __restrict__ x, const float* __restrict__ dinv,
                                   unsigned* __restrict__ xb) {
    int i = blockIdx.x * blockDim.x + threadIdx.x;
    if (i < N_EDGES) {
        int c = cols[i];
        int pos = atomicAdd(&cursor[c], 1);
        eidx[pos] = rows[i];
    }
    if (i < N_NODES * (F_IN / 8)) {  // 800000 exactly
        int node = i >> 4;
        float d = dinv[node];
        float4 a = ((const float4*)x)[(size_t)i * 2];
        float4 b = ((const float4*)x)[(size_t)i * 2 + 1];
        uint4 o;
        o.x = f2bf(d * a.x) | (f2bf(d * a.y) << 16);
        o.y = f2bf(d * a.z) | (f2bf(d * a.w) << 16);
        o.z = f2bf(d * b.x) | (f2bf(d * b.y) << 16);
        o.w = f2bf(d * b.z) | (f2bf(d * b.w) << 16);
        ((uint4*)xb)[i] = o;
    }
}

// ---------------- fused: bf16-gather(pre-scaled) -> @W1+b1+relu -> Hchunk -> @W2 -> t2b ----
// 32-node tile, 256 threads. LDS 24576 B: Ax[32][128]f32 (16K) + Bs[8][256] (8K);
// phase C Hchunk[32][66] aliases Ax.
__global__ __launch_bounds__(256, 4) void fused12_kernel(const unsigned* __restrict__ xb,
                                                         const int* __restrict__ row_ptr,
                                                         const int* __restrict__ eidx,
                                                         const float* __restrict__ dinv,
                                                         const float* __restrict__ W1,
                                                         const float* __restrict__ b1,
                                                         const float* __restrict__ W2,
                                                         unsigned* __restrict__ t2b) {
    __shared__ __align__(16) char smem_raw[24576];
    float* Ax = (float*)smem_raw;              // [32][128]
    float* Bs = (float*)(smem_raw + 16384);    // [8][256]
    float* Hc = (float*)smem_raw;              // [32][66] (phase C, aliases Ax)

    int tid = threadIdx.x;
    int bm0 = blockIdx.x * 32;

    // ---- phase A: gather (pre-scaled rows; single dependent load per edge), unroll-8 ----
    {
        int f8 = tid & 15;   // feature octet
        int ng = tid >> 4;   // 0..15
        for (int p = 0; p < 2; ++p) {
            int nl = p * 16 + ng;
            int c = bm0 + nl;
            float acc[8] = {};
            if (c < N_NODES) {
                uint4 S = ((const uint4*)xb)[(size_t)c * 16 + f8];  // self (pre-scaled)
                acc[0] = bflo(S.x); acc[1] = bfhi(S.x);
                acc[2] = bflo(S.y); acc[3] = bfhi(S.y);
                acc[4] = bflo(S.z); acc[5] = bfhi(S.z);
                acc[6] = bflo(S.w); acc[7] = bfhi(S.w);
                int k = row_ptr[c];
                int k1 = row_ptr[c + 1];
                for (; k < k1; k += 8) {
                    int r[8];
                    float m[8];
#pragma unroll
                    for (int j = 0; j < 8; ++j) {
                        int idx = (k + j < k1) ? k + j : k1 - 1;
                        r[j] = eidx[idx];
                        m[j] = (k + j < k1) ? 1.f : 0.f;
                    }
                    uint4 U[8];
#pragma unroll
                    for (int j = 0; j < 8; ++j) U[j] = ((const uint4*)xb)[(size_t)r[j] * 16 + f8];
#pragma unroll
                    for (int j = 0; j < 8; ++j) {
                        acc[0] = fmaf(m[j], bflo(U[j].x), acc[0]);
                        acc[1] = fmaf(m[j], bfhi(U[j].x), acc[1]);
                        acc[2] = fmaf(m[j], bflo(U[j].y), acc[2]);
                        acc[3] = fmaf(m[j], bfhi(U[j].y), acc[3]);
                        acc[4] = fmaf(m[j], bflo(U[j].z), acc[4]);
                        acc[5] = fmaf(m[j], bfhi(U[j].z), acc[5]);
                        acc[6] = fmaf(m[j], bflo(U[j].w), acc[6]);
                        acc[7] = fmaf(m[j], bfhi(U[j].w), acc[7]);
                    }
                }
                float dc = dinv[c];
#pragma unroll
                for (int q = 0; q < 8; ++q) acc[q] *= dc;
            }
            *(float4*)&Ax[nl * 128 + f8 * 8] = make_float4(acc[0], acc[1], acc[2], acc[3]);
            *(float4*)&Ax[nl * 128 + f8 * 8 + 4] = make_float4(acc[4], acc[5], acc[6], acc[7]);
        }
    }
    __syncthreads();

    // ---- phase B: acc1[32x256] = Ax @ W1 ----
    int tx = tid & 15;
    int ty = tid >> 4;
    float acc1[2][4][4] = {};

    for (int k0 = 0; k0 < F_IN; k0 += 8) {
        {
            int bk = tid >> 5;
            int c8 = tid & 31;
            const float4* src = (const float4*)&W1[(size_t)(k0 + bk) * F_HID + c8 * 8];
            float4 u0 = src[0];
            float4 u1 = src[1];
            ((float4*)&Bs[bk * 256 + c8 * 8])[0] = u0;
            ((float4*)&Bs[bk * 256 + c8 * 8])[1] = u1;
        }
        __syncthreads();
#pragma unroll
        for (int kk4 = 0; kk4 < 2; ++kk4) {
            float4 a4[2];
#pragma unroll
            for (int i = 0; i < 2; ++i)
                a4[i] = *(const float4*)&Ax[(ty * 2 + i) * 128 + k0 + kk4 * 4];
#pragma unroll
            for (int q4 = 0; q4 < 4; ++q4) {
                int kk = kk4 * 4 + q4;
                float a[2];
                a[0] = (q4 == 0) ? a4[0].x : (q4 == 1) ? a4[0].y : (q4 == 2) ? a4[0].z : a4[0].w;
                a[1] = (q4 == 0) ? a4[1].x : (q4 == 1) ? a4[1].y : (q4 == 2) ? a4[1].z : a4[1].w;
                float b[4][4];
#pragma unroll
                for (int jg = 0; jg < 4; ++jg) {
                    float4 bb = *(const float4*)&Bs[kk * 256 + jg * 64 + tx * 4];
                    b[jg][0] = bb.x; b[jg][1] = bb.y; b[jg][2] = bb.z; b[jg][3] = bb.w;
                }
#pragma unroll
                for (int i = 0; i < 2; ++i)
#pragma unroll
                    for (int jg = 0; jg < 4; ++jg)
#pragma unroll
                        for (int q = 0; q < 4; ++q)
                            acc1[i][jg][q] = fmaf(a[i], b[jg][q], acc1[i][jg][q]);
            }
        }
        __syncthreads();
    }

    // ---- phase C: chunked H (64 cols) -> acc2 += Hc @ W2chunk (W2 direct from cache) ----
    float acc2[2][4] = {};
#pragma unroll
    for (int jg = 0; jg < 4; ++jg) {
#pragma unroll
        for (int i = 0; i < 2; ++i) {
            int col = jg * 64 + tx * 4;
            float4 bias = *(const float4*)&b1[col];
            Hc[(ty * 2 + i) * 66 + tx * 4 + 0] = fmaxf(acc1[i][jg][0] + bias.x, 0.f);
            Hc[(ty * 2 + i) * 66 + tx * 4 + 1] = fmaxf(acc1[i][jg][1] + bias.y, 0.f);
            Hc[(ty * 2 + i) * 66 + tx * 4 + 2] = fmaxf(acc1[i][jg][2] + bias.z, 0.f);
            Hc[(ty * 2 + i) * 66 + tx * 4 + 3] = fmaxf(acc1[i][jg][3] + bias.w, 0.f);
        }
        __syncthreads();
        const float4* W2r = (const float4*)W2;
#pragma unroll 8
        for (int k = 0; k < 64; ++k) {
            float a0 = Hc[(ty * 2 + 0) * 66 + k];
            float a1 = Hc[(ty * 2 + 1) * 66 + k];
            float4 bb = W2r[(size_t)(jg * 64 + k) * 16 + tx];
            acc2[0][0] = fmaf(a0, bb.x, acc2[0][0]);
            acc2[0][1] = fmaf(a0, bb.y, acc2[0][1]);
            acc2[0][2] = fmaf(a0, bb.z, acc2[0][2]);
            acc2[0][3] = fmaf(a0, bb.w, acc2[0][3]);
            acc2[1][0] = fmaf(a1, bb.x, acc2[1][0]);
            acc2[1][1] = fmaf(a1, bb.y, acc2[1][1]);
            acc2[1][2] = fmaf(a1, bb.z, acc2[1][2]);
            acc2[1][3] = fmaf(a1, bb.w, acc2[1][3]);
        }
        __syncthreads();
    }

    // ---- write t2b = bf16(dinv * acc2) ----
#pragma unroll
    for (int i = 0; i < 2; ++i) {
        int row = bm0 + ty * 2 + i;
        if (row >= N_NODES) continue;
        float d = dinv[row];
        uint2 o;
        o.x = f2bf(d * acc2[i][0]) | (f2bf(d * acc2[i][1]) << 16);
        o.y = f2bf(d * acc2[i][2]) | (f2bf(d * acc2[i][3]) << 16);
        *(uint2*)((unsigned short*)t2b + (size_t)row * 64 + tx * 4) = o;
    }
}

// ---------------- layer 2 pull-gather (bf16, pre-scaled), unroll-8 ----------------
__global__ __launch_bounds__(256) void l2_gather_kernel(const unsigned* __restrict__ t2b,
                                                        const int* __restrict__ row_ptr,
                                                        const int* __restrict__ eidx,
                                                        const float* __restrict__ dinv,
                                                        const float* __restrict__ b2,
                                                        float* __restrict__ out) {
    int tid = threadIdx.x;
    int f8 = tid & 7;    // feature octet (64 feats)
    int nl = tid >> 3;   // 0..31
    int c = blockIdx.x * 32 + nl;
    if (c >= N_NODES) return;
    uint4 S = ((const uint4*)t2b)[(size_t)c * 8 + f8];
    float acc[8];
    acc[0] = bflo(S.x); acc[1] = bfhi(S.x);
    acc[2] = bflo(S.y); acc[3] = bfhi(S.y);
    acc[4] = bflo(S.z); acc[5] = bfhi(S.z);
    acc[6] = bflo(S.w); acc[7] = bfhi(S.w);
    int k = row_ptr[c];
    int k1 = row_ptr[c + 1];
    for (; k < k1; k += 8) {
        int r[8];
        float m[8];
#pragma unroll
        for (int j = 0; j < 8; ++j) {
            int idx = (k + j < k1) ? k + j : k1 - 1;
            r[j] = eidx[idx];
            m[j] = (k + j < k1) ? 1.f : 0.f;
        }
        uint4 U[8];
#pragma unroll
        for (int j = 0; j < 8; ++j) U[j] = ((const uint4*)t2b)[(size_t)r[j] * 8 + f8];
#pragma unroll
        for (int j = 0; j < 8; ++j) {
            acc[0] = fmaf(m[j], bflo(U[j].x), acc[0]);
            acc[1] = fmaf(m[j], bfhi(U[j].x), acc[1]);
            acc[2] = fmaf(m[j], bflo(U[j].y), acc[2]);
            acc[3] = fmaf(m[j], bfhi(U[j].y), acc[3]);
            acc[4] = fmaf(m[j], bflo(U[j].z), acc[4]);
            acc[5] = fmaf(m[j], bfhi(U[j].z), acc[5]);
            acc[6] = fmaf(m[j], bflo(U[j].w), acc[6]);
            acc[7] = fmaf(m[j], bfhi(U[j].w), acc[7]);
        }
    }
    float dc = dinv[c];
    float4 b2a = *(const float4*)&b2[f8 * 8];
    float4 b2b = *(const float4*)&b2[f8 * 8 + 4];
    float4 o0, o1;
    o0.x = fmaf(dc, acc[0], b2a.x);
    o0.y = fmaf(dc, acc[1], b2a.y);
    o0.z = fmaf(dc, acc[2], b2a.z);
    o0.w = fmaf(dc, acc[3], b2a.w);
    o1.x = fmaf(dc, acc[4], b2b.x);
    o1.y = fmaf(dc, acc[5], b2b.y);
    o1.z = fmaf(dc, acc[6], b2b.z);
    o1.w = fmaf(dc, acc[7], b2b.w);
    ((float4*)out)[(size_t)c * 16 + f8 * 2] = o0;
    ((float4*)out)[(size_t)c * 16 + f8 * 2 + 1] = o1;
}

// ---------------- launch ----------------

extern "C" void kernel_launch(void* const* d_in, const int* in_sizes, int n_in,
                              void* d_out, int out_size, void* d_ws, size_t ws_size,
                              hipStream_t stream) {
    const float* x = (const float*)d_in[0];
    const int* edge_index = (const int*)d_in[1];
    const float* W1 = (const float*)d_in[2];
    const float* b1 = (const float*)d_in[3];
    const float* W2 = (const float*)d_in[4];
    const float* b2 = (const float*)d_in[5];
    float* out = (float*)d_out;

    const int* rows = edge_index;            // source nodes
    const int* cols = edge_index + N_EDGES;  // target nodes

    char* ws = (char*)d_ws;
    int* row_ptr = (int*)(ws + OFF_ROWPTR);
    int* cnt = (int*)(ws + OFF_CNT);
    int* cursor = (int*)(ws + OFF_CURSOR);
    float* dinv = (float*)(ws + OFF_DINV);
    int* eidx = (int*)(ws + OFF_EIDX);
    unsigned* xb = (unsigned*)(ws + OFF_XB);
    unsigned* t2b = (unsigned*)(ws + OFF_T2B);

    const int BT = 256;

    zero_cnt_kernel<<<(N_NODES + BT - 1) / BT, BT, 0, stream>>>(cnt, N_NODES);
    hist_kernel<<<(N_EDGES + BT - 1) / BT, BT, 0, stream>>>(cols, cnt, N_EDGES);
    scan_kernel<<<1, 1024, 0, stream>>>(cnt, row_ptr, cursor, dinv);
    scatter_cvt_kernel<<<(N_EDGES + BT - 1) / BT, BT, 0, stream>>>(rows, cols, cursor, eidx, x, dinv, xb);

    fused12_kernel<<<(N_NODES + 31) / 32, 256, 0, stream>>>(xb, row_ptr, eidx, dinv, W1, b1, W2, t2b);
    l2_gather_kernel<<<(N_NODES + 31) / 32, 256, 0, stream>>>(t2b, row_ptr, eidx, dinv, b2, out);
}

// Round 13
// 222.019 us; speedup vs baseline: 1.6958x; 1.6958x over previous
//
#include <hip/hip_runtime.h>

#define N_NODES 50000
#define N_EDGES 800000
#define F_IN 128
#define F_HID 256
#define F_OUT 64

#define SCAN_NB ((N_NODES + 255) / 256)  // 196

// ---------------- workspace layout (bytes) ----------------
// row_ptr @ 0.00 MiB: int[N+1]
// cnt     @ 0.25 MiB: int[N]
// cursor  @ 0.50 MiB: int[N]
// dinv    @ 0.75 MiB: f32[N]
// bsum    @ 0.96 MiB: int[256]
// eidx    @ 1.00 MiB: int[E]          (3.2 MB)
// xb      @ 4.25 MiB: bf16[N,128]     (12.8 MB)  (pre-scaled by dinv)
// t2b     @ 17.5 MiB: bf16[N,64]      (6.4 MB)

#define OFF_ROWPTR 0ull
#define OFF_CNT    (256ull << 10)
#define OFF_CURSOR (512ull << 10)
#define OFF_DINV   (768ull << 10)
#define OFF_BSUM   (984ull << 10)
#define OFF_EIDX   (1ull << 20)
#define OFF_XB     ((4ull << 20) + (256ull << 10))
#define OFF_T2B    ((17ull << 20) + (512ull << 10))

// ---------------- bf16 helpers ----------------

__device__ __forceinline__ unsigned f2bf(float f) {  // RNE to bf16 (low 16 bits)
    unsigned u = __float_as_uint(f);
    return (u + 0x7FFFu + ((u >> 16) & 1u)) >> 16;
}
__device__ __forceinline__ float bflo(unsigned u) { return __uint_as_float(u << 16); }
__device__ __forceinline__ float bfhi(unsigned u) { return __uint_as_float(u & 0xFFFF0000u); }

// ---------------- CSR build ----------------

__global__ void zero_cnt_kernel(int* __restrict__ cnt, int n) {
    int i = blockIdx.x * blockDim.x + threadIdx.x;
    if (i < n) cnt[i] = 0;
}

__global__ void hist_kernel(const int* __restrict__ cols, int* __restrict__ cnt, int e) {
    int i = blockIdx.x * blockDim.x + threadIdx.x;
    if (i < e) atomicAdd(&cnt[cols[i]], 1);
}

// (1) per-block sums of cnt
__global__ __launch_bounds__(256) void bsum_kernel(const int* __restrict__ cnt, int* __restrict__ bsum) {
    __shared__ int s[256];
    int t = threadIdx.x;
    int i = blockIdx.x * 256 + t;
    int v = (i < N_NODES) ? cnt[i] : 0;
    s[t] = v;
    __syncthreads();
#pragma unroll
    for (int off = 128; off > 0; off >>= 1) {
        if (t < off) s[t] += s[t + off];
        __syncthreads();
    }
    if (t == 0) bsum[blockIdx.x] = s[0];
}

// (2) exclusive scan of the block sums (single small block)
__global__ __launch_bounds__(256) void bscan_kernel(int* __restrict__ bsum) {
    __shared__ int s[256];
    int t = threadIdx.x;
    int v = (t < SCAN_NB) ? bsum[t] : 0;
    s[t] = v;
    __syncthreads();
#pragma unroll
    for (int off = 1; off < 256; off <<= 1) {
        int u = (t >= off) ? s[t - off] : 0;
        __syncthreads();
        s[t] += u;
        __syncthreads();
    }
    if (t < SCAN_NB) bsum[t] = s[t] - v;  // exclusive
}

// (3) intra-block prefix + block offset -> row_ptr, cursor, dinv
__global__ __launch_bounds__(256) void rowptr_kernel(const int* __restrict__ cnt,
                                                     const int* __restrict__ bsum,
                                                     int* __restrict__ row_ptr,
                                                     int* __restrict__ cursor,
                                                     float* __restrict__ dinv) {
    __shared__ int s[256];
    int t = threadIdx.x;
    int i = blockIdx.x * 256 + t;
    int v = (i < N_NODES) ? cnt[i] : 0;
    s[t] = v;
    __syncthreads();
#pragma unroll
    for (int off = 1; off < 256; off <<= 1) {
        int u = (t >= off) ? s[t - off] : 0;
        __syncthreads();
        s[t] += u;
        __syncthreads();
    }
    int excl = s[t] - v + bsum[blockIdx.x];
    if (i < N_NODES) {
        row_ptr[i] = excl;
        cursor[i] = excl;
        dinv[i] = rsqrtf((float)v + 1.0f);  // +1 self loop
    }
    if (blockIdx.x == 0 && t == 0) row_ptr[N_NODES] = N_EDGES;
}

// scatter edge ids into CSR slots AND convert x -> pre-scaled bf16 (same 800k grid)
__global__ void scatter_cvt_kernel(const int* __restrict__ rows, const int* __restrict__ cols,
                                   int* __restrict__ cursor, int* __restrict__ eidx,
                                   const float* __restrict__ x, const float* __restrict__ dinv,
                                   unsigned* __restrict__ xb) {
    int i = blockIdx.x * blockDim.x + threadIdx.x;
    if (i < N_EDGES) {
        int c = cols[i];
        int pos = atomicAdd(&cursor[c], 1);
        eidx[pos] = rows[i];
    }
    if (i < N_NODES * (F_IN / 8)) {  // 800000 exactly
        int node = i >> 4;
        float d = dinv[node];
        float4 a = ((const float4*)x)[(size_t)i * 2];
        float4 b = ((const float4*)x)[(size_t)i * 2 + 1];
        uint4 o;
        o.x = f2bf(d * a.x) | (f2bf(d * a.y) << 16);
        o.y = f2bf(d * a.z) | (f2bf(d * a.w) << 16);
        o.z = f2bf(d * b.x) | (f2bf(d * b.y) << 16);
        o.w = f2bf(d * b.z) | (f2bf(d * b.w) << 16);
        ((uint4*)xb)[i] = o;
    }
}

// ---------------- fused: bf16-gather(pre-scaled) -> @W1+b1+relu -> Hchunk -> @W2 -> t2b ----
__global__ __launch_bounds__(256, 4) void fused12_kernel(const unsigned* __restrict__ xb,
                                                         const int* __restrict__ row_ptr,
                                                         const int* __restrict__ eidx,
                                                         const float* __restrict__ dinv,
                                                         const float* __restrict__ W1,
                                                         const float* __restrict__ b1,
                                                         const float* __restrict__ W2,
                                                         unsigned* __restrict__ t2b) {
    __shared__ __align__(16) char smem_raw[24576];
    float* Ax = (float*)smem_raw;              // [32][128]
    float* Bs = (float*)(smem_raw + 16384);    // [8][256]
    float* Hc = (float*)smem_raw;              // [32][66] (phase C, aliases Ax)

    int tid = threadIdx.x;
    int bm0 = blockIdx.x * 32;

    // ---- phase A: gather (pre-scaled rows), unroll-8 ----
    {
        int f8 = tid & 15;   // feature octet
        int ng = tid >> 4;   // 0..15
        for (int p = 0; p < 2; ++p) {
            int nl = p * 16 + ng;
            int c = bm0 + nl;
            float acc[8] = {};
            if (c < N_NODES) {
                uint4 S = ((const uint4*)xb)[(size_t)c * 16 + f8];  // self (pre-scaled)
                acc[0] = bflo(S.x); acc[1] = bfhi(S.x);
                acc[2] = bflo(S.y); acc[3] = bfhi(S.y);
                acc[4] = bflo(S.z); acc[5] = bfhi(S.z);
                acc[6] = bflo(S.w); acc[7] = bfhi(S.w);
                int k = row_ptr[c];
                int k1 = row_ptr[c + 1];
                for (; k < k1; k += 8) {
                    int r[8];
                    float m[8];
#pragma unroll
                    for (int j = 0; j < 8; ++j) {
                        int idx = (k + j < k1) ? k + j : k1 - 1;
                        r[j] = eidx[idx];
                        m[j] = (k + j < k1) ? 1.f : 0.f;
                    }
                    uint4 U[8];
#pragma unroll
                    for (int j = 0; j < 8; ++j) U[j] = ((const uint4*)xb)[(size_t)r[j] * 16 + f8];
#pragma unroll
                    for (int j = 0; j < 8; ++j) {
                        acc[0] = fmaf(m[j], bflo(U[j].x), acc[0]);
                        acc[1] = fmaf(m[j], bfhi(U[j].x), acc[1]);
                        acc[2] = fmaf(m[j], bflo(U[j].y), acc[2]);
                        acc[3] = fmaf(m[j], bfhi(U[j].y), acc[3]);
                        acc[4] = fmaf(m[j], bflo(U[j].z), acc[4]);
                        acc[5] = fmaf(m[j], bfhi(U[j].z), acc[5]);
                        acc[6] = fmaf(m[j], bflo(U[j].w), acc[6]);
                        acc[7] = fmaf(m[j], bfhi(U[j].w), acc[7]);
                    }
                }
                float dc = dinv[c];
#pragma unroll
                for (int q = 0; q < 8; ++q) acc[q] *= dc;
            }
            *(float4*)&Ax[nl * 128 + f8 * 8] = make_float4(acc[0], acc[1], acc[2], acc[3]);
            *(float4*)&Ax[nl * 128 + f8 * 8 + 4] = make_float4(acc[4], acc[5], acc[6], acc[7]);
        }
    }
    __syncthreads();

    // ---- phase B: acc1[32x256] = Ax @ W1 ----
    int tx = tid & 15;
    int ty = tid >> 4;
    float acc1[2][4][4] = {};

    for (int k0 = 0; k0 < F_IN; k0 += 8) {
        {
            int bk = tid >> 5;
            int c8 = tid & 31;
            const float4* src = (const float4*)&W1[(size_t)(k0 + bk) * F_HID + c8 * 8];
            float4 u0 = src[0];
            float4 u1 = src[1];
            ((float4*)&Bs[bk * 256 + c8 * 8])[0] = u0;
            ((float4*)&Bs[bk * 256 + c8 * 8])[1] = u1;
        }
        __syncthreads();
#pragma unroll
        for (int kk4 = 0; kk4 < 2; ++kk4) {
            float4 a4[2];
#pragma unroll
            for (int i = 0; i < 2; ++i)
                a4[i] = *(const float4*)&Ax[(ty * 2 + i) * 128 + k0 + kk4 * 4];
#pragma unroll
            for (int q4 = 0; q4 < 4; ++q4) {
                int kk = kk4 * 4 + q4;
                float a[2];
                a[0] = (q4 == 0) ? a4[0].x : (q4 == 1) ? a4[0].y : (q4 == 2) ? a4[0].z : a4[0].w;
                a[1] = (q4 == 0) ? a4[1].x : (q4 == 1) ? a4[1].y : (q4 == 2) ? a4[1].z : a4[1].w;
                float b[4][4];
#pragma unroll
                for (int jg = 0; jg < 4; ++jg) {
                    float4 bb = *(const float4*)&Bs[kk * 256 + jg * 64 + tx * 4];
                    b[jg][0] = bb.x; b[jg][1] = bb.y; b[jg][2] = bb.z; b[jg][3] = bb.w;
                }
#pragma unroll
                for (int i = 0; i < 2; ++i)
#pragma unroll
                    for (int jg = 0; jg < 4; ++jg)
#pragma unroll
                        for (int q = 0; q < 4; ++q)
                            acc1[i][jg][q] = fmaf(a[i], b[jg][q], acc1[i][jg][q]);
            }
        }
        __syncthreads();
    }

    // ---- phase C: chunked H (64 cols) -> acc2 += Hc @ W2chunk ----
    float acc2[2][4] = {};
#pragma unroll
    for (int jg = 0; jg < 4; ++jg) {
#pragma unroll
        for (int i = 0; i < 2; ++i) {
            int col = jg * 64 + tx * 4;
            float4 bias = *(const float4*)&b1[col];
            Hc[(ty * 2 + i) * 66 + tx * 4 + 0] = fmaxf(acc1[i][jg][0] + bias.x, 0.f);
            Hc[(ty * 2 + i) * 66 + tx * 4 + 1] = fmaxf(acc1[i][jg][1] + bias.y, 0.f);
            Hc[(ty * 2 + i) * 66 + tx * 4 + 2] = fmaxf(acc1[i][jg][2] + bias.z, 0.f);
            Hc[(ty * 2 + i) * 66 + tx * 4 + 3] = fmaxf(acc1[i][jg][3] + bias.w, 0.f);
        }
        __syncthreads();
        const float4* W2r = (const float4*)W2;
#pragma unroll 8
        for (int k = 0; k < 64; ++k) {
            float a0 = Hc[(ty * 2 + 0) * 66 + k];
            float a1 = Hc[(ty * 2 + 1) * 66 + k];
            float4 bb = W2r[(size_t)(jg * 64 + k) * 16 + tx];
            acc2[0][0] = fmaf(a0, bb.x, acc2[0][0]);
            acc2[0][1] = fmaf(a0, bb.y, acc2[0][1]);
            acc2[0][2] = fmaf(a0, bb.z, acc2[0][2]);
            acc2[0][3] = fmaf(a0, bb.w, acc2[0][3]);
            acc2[1][0] = fmaf(a1, bb.x, acc2[1][0]);
            acc2[1][1] = fmaf(a1, bb.y, acc2[1][1]);
            acc2[1][2] = fmaf(a1, bb.z, acc2[1][2]);
            acc2[1][3] = fmaf(a1, bb.w, acc2[1][3]);
        }
        __syncthreads();
    }

    // ---- write t2b = bf16(dinv * acc2) ----
#pragma unroll
    for (int i = 0; i < 2; ++i) {
        int row = bm0 + ty * 2 + i;
        if (row >= N_NODES) continue;
        float d = dinv[row];
        uint2 o;
        o.x = f2bf(d * acc2[i][0]) | (f2bf(d * acc2[i][1]) << 16);
        o.y = f2bf(d * acc2[i][2]) | (f2bf(d * acc2[i][3]) << 16);
        *(uint2*)((unsigned short*)t2b + (size_t)row * 64 + tx * 4) = o;
    }
}

// ---------------- layer 2 pull-gather (bf16, pre-scaled), unroll-8 ----------------
__global__ __launch_bounds__(256) void l2_gather_kernel(const unsigned* __restrict__ t2b,
                                                        const int* __restrict__ row_ptr,
                                                        const int* __restrict__ eidx,
                                                        const float* __restrict__ dinv,
                                                        const float* __restrict__ b2,
                                                        float* __restrict__ out) {
    int tid = threadIdx.x;
    int f8 = tid & 7;    // feature octet (64 feats)
    int nl = tid >> 3;   // 0..31
    int c = blockIdx.x * 32 + nl;
    if (c >= N_NODES) return;
    uint4 S = ((const uint4*)t2b)[(size_t)c * 8 + f8];
    float acc[8];
    acc[0] = bflo(S.x); acc[1] = bfhi(S.x);
    acc[2] = bflo(S.y); acc[3] = bfhi(S.y);
    acc[4] = bflo(S.z); acc[5] = bfhi(S.z);
    acc[6] = bflo(S.w); acc[7] = bfhi(S.w);
    int k = row_ptr[c];
    int k1 = row_ptr[c + 1];
    for (; k < k1; k += 8) {
        int r[8];
        float m[8];
#pragma unroll
        for (int j = 0; j < 8; ++j) {
            int idx = (k + j < k1) ? k + j : k1 - 1;
            r[j] = eidx[idx];
            m[j] = (k + j < k1) ? 1.f : 0.f;
        }
        uint4 U[8];
#pragma unroll
        for (int j = 0; j < 8; ++j) U[j] = ((const uint4*)t2b)[(size_t)r[j] * 8 + f8];
#pragma unroll
        for (int j = 0; j < 8; ++j) {
            acc[0] = fmaf(m[j], bflo(U[j].x), acc[0]);
            acc[1] = fmaf(m[j], bfhi(U[j].x), acc[1]);
            acc[2] = fmaf(m[j], bflo(U[j].y), acc[2]);
            acc[3] = fmaf(m[j], bfhi(U[j].y), acc[3]);
            acc[4] = fmaf(m[j], bflo(U[j].z), acc[4]);
            acc[5] = fmaf(m[j], bfhi(U[j].z), acc[5]);
            acc[6] = fmaf(m[j], bflo(U[j].w), acc[6]);
            acc[7] = fmaf(m[j], bfhi(U[j].w), acc[7]);
        }
    }
    float dc = dinv[c];
    float4 b2a = *(const float4*)&b2[f8 * 8];
    float4 b2b = *(const float4*)&b2[f8 * 8 + 4];
    float4 o0, o1;
    o0.x = fmaf(dc, acc[0], b2a.x);
    o0.y = fmaf(dc, acc[1], b2a.y);
    o0.z = fmaf(dc, acc[2], b2a.z);
    o0.w = fmaf(dc, acc[3], b2a.w);
    o1.x = fmaf(dc, acc[4], b2b.x);
    o1.y = fmaf(dc, acc[5], b2b.y);
    o1.z = fmaf(dc, acc[6], b2b.z);
    o1.w = fmaf(dc, acc[7], b2b.w);
    ((float4*)out)[(size_t)c * 16 + f8 * 2] = o0;
    ((float4*)out)[(size_t)c * 16 + f8 * 2 + 1] = o1;
}

// ---------------- launch ----------------

extern "C" void kernel_launch(void* const* d_in, const int* in_sizes, int n_in,
                              void* d_out, int out_size, void* d_ws, size_t ws_size,
                              hipStream_t stream) {
    const float* x = (const float*)d_in[0];
    const int* edge_index = (const int*)d_in[1];
    const float* W1 = (const float*)d_in[2];
    const float* b1 = (const float*)d_in[3];
    const float* W2 = (const float*)d_in[4];
    const float* b2 = (const float*)d_in[5];
    float* out = (float*)d_out;

    const int* rows = edge_index;            // source nodes
    const int* cols = edge_index + N_EDGES;  // target nodes

    char* ws = (char*)d_ws;
    int* row_ptr = (int*)(ws + OFF_ROWPTR);
    int* cnt = (int*)(ws + OFF_CNT);
    int* cursor = (int*)(ws + OFF_CURSOR);
    float* dinv = (float*)(ws + OFF_DINV);
    int* bsum = (int*)(ws + OFF_BSUM);
    int* eidx = (int*)(ws + OFF_EIDX);
    unsigned* xb = (unsigned*)(ws + OFF_XB);
    unsigned* t2b = (unsigned*)(ws + OFF_T2B);

    const int BT = 256;

    zero_cnt_kernel<<<(N_NODES + BT - 1) / BT, BT, 0, stream>>>(cnt, N_NODES);
    hist_kernel<<<(N_EDGES + BT - 1) / BT, BT, 0, stream>>>(cols, cnt, N_EDGES);
    bsum_kernel<<<SCAN_NB, 256, 0, stream>>>(cnt, bsum);
    bscan_kernel<<<1, 256, 0, stream>>>(bsum);
    rowptr_kernel<<<SCAN_NB, 256, 0, stream>>>(cnt, bsum, row_ptr, cursor, dinv);
    scatter_cvt_kernel<<<(N_EDGES + BT - 1) / BT, BT, 0, stream>>>(rows, cols, cursor, eidx, x, dinv, xb);

    fused12_kernel<<<(N_NODES + 31) / 32, 256, 0, stream>>>(xb, row_ptr, eidx, dinv, W1, b1, W2, t2b);
    l2_gather_kernel<<<(N_NODES + 31) / 32, 256, 0, stream>>>(t2b, row_ptr, eidx, dinv, b2, out);
}